// Round 15
// baseline (547.996 us; speedup 1.0000x reference)
//
#include <hip/hip_runtime.h>

#define N 512
#define L 8192

#define LOG_MIN -6.907755278982137f
#define LOG_MAX -2.302585092994046f

typedef __attribute__((ext_vector_type(8))) short short8;
typedef __attribute__((ext_vector_type(4))) float f4;
typedef __attribute__((ext_vector_type(4))) unsigned u4;

__device__ __forceinline__ float get_delta(const float* logd) {
  float ld = logd[0];
  ld = fminf(fmaxf(ld, LOG_MIN), LOG_MAX);
  return expf(ld);
}
__device__ __forceinline__ unsigned short f2bf(float x) {
  union { float f; unsigned int u; } c; c.f = x;
  unsigned int u = c.u;
  u += 0x7FFFu + ((u >> 16) & 1u);
  return (unsigned short)(u >> 16);
}
__device__ __forceinline__ unsigned int pack2(unsigned short a, unsigned short b) {
  return (unsigned int)a | ((unsigned int)b << 16);
}
__device__ __forceinline__ void wts4(float* p, f4 v) { *(f4*)p = v; }
__device__ __forceinline__ void wts4u(unsigned* p, u4 v) { *(u4*)p = v; }

// ---------------------------------------------------------------------------
// ws layout (floats):
//   0        kvec (8192) | 8192 Vtr (128*512) | 73728 W (64*512)
//   106496   Xi (512*512)
//   368640   PB[12] (12*512*512)   Ad^2 .. Ad^4096
//   3514368  Atab (1MB) | 3776512 Btab (512KB) | 3907584 Dinv (16*1024)
// ---------------------------------------------------------------------------

// 32x32 diag-block inverse of A1 = I - h*A -> Dinv[d]. Wave-parallel subst.
__device__ void diag32inv(const float* __restrict__ A, float h,
                          float* __restrict__ Dinv, int d, int tid) {
  __shared__ float Ash[32][33];
  __shared__ float xs[32][33];
  __shared__ float dv[32];
  int i0 = d * 32;
  {
    int r = tid >> 3, c4 = (tid & 7) * 4;
    f4 v = *(const f4*)(A + (size_t)(i0 + r) * N + i0 + c4);
    Ash[r][c4] = v.x; Ash[r][c4 + 1] = v.y; Ash[r][c4 + 2] = v.z; Ash[r][c4 + 3] = v.w;
  }
  for (int i = tid; i < 32 * 33; i += 256) ((float*)xs)[i] = 0.f;
  __syncthreads();
  if (tid < 32) dv[tid] = 1.f / (1.f - h * Ash[tid][tid]);
  __syncthreads();
  int t = tid >> 3, kl = tid & 7;
  for (int rr = 0; rr < 32; ++rr) {
    float s = 0.f;
    for (int k = t + kl; k < rr; k += 8) s += Ash[rr][k] * xs[k][t];
    s += __shfl_xor(s, 1, 64);
    s += __shfl_xor(s, 2, 64);
    s += __shfl_xor(s, 4, 64);
    if (kl == 0 && t <= rr)
      xs[rr][t] = (((rr == t) ? 1.f : 0.f) + h * s) * dv[rr];
    __syncthreads();
  }
  {
    int r = tid >> 3, c4 = (tid & 7) * 4;
    f4 v = {xs[r][c4], xs[r][c4 + 1], xs[r][c4 + 2], xs[r][c4 + 3]};
    *(f4*)(Dinv + d * 1024 + r * 32 + c4) = v;
  }
}

// 32x32-tile lower-tri squaring (first: P := 2P - I on read).
__device__ void sq32(const float* __restrict__ P, float* __restrict__ Q,
                     int bi, int bj, int first, int tid, float* sm) {
  float* As = sm;
  float* Bs = sm + 1056;   // [32][36]
  int lr = tid >> 3, lc = (tid & 7) * 4;
  int nk = bi - bj + 1;
  int kb0 = bj * 32;
  int arow = bi * 32 + lr;
  const float* ap = P + (size_t)arow * N + lc;
  const float* bp = P + bj * 32 + lc;
  f4 aR[16], bR[16];
#pragma unroll
  for (int t = 0; t < 16; ++t) {
    if (t < nk) {
      int kt = kb0 + 32 * t;
      aR[t] = *(const f4*)(ap + kt);
      bR[t] = *(const f4*)(bp + (size_t)(kt + lr) * N);
    }
  }
  float acc[4] = {0.f, 0.f, 0.f, 0.f};
#pragma unroll
  for (int t = 0; t < 16; ++t) {
    if (t < nk) {
      int kb = kb0 + 32 * t;
      float a4[4] = {aR[t].x, aR[t].y, aR[t].z, aR[t].w};
      float b4[4] = {bR[t].x, bR[t].y, bR[t].z, bR[t].w};
      if (first) {
#pragma unroll
        for (int j = 0; j < 4; ++j) {
          a4[j] = 2.f * a4[j] - ((arow == kb + lc + j) ? 1.f : 0.f);
          b4[j] = 2.f * b4[j] - ((kb + lr == bj * 32 + lc + j) ? 1.f : 0.f);
        }
      }
      As[lr * 33 + lc] = a4[0]; As[lr * 33 + lc + 1] = a4[1];
      As[lr * 33 + lc + 2] = a4[2]; As[lr * 33 + lc + 3] = a4[3];
      f4 bv = {b4[0], b4[1], b4[2], b4[3]};
      *(f4*)&Bs[lr * 36 + lc] = bv;
      __syncthreads();
#pragma unroll
      for (int kk = 0; kk < 32; ++kk) {
        float a = As[lr * 33 + kk];
        f4 bb = *(const f4*)&Bs[kk * 36 + lc];
        acc[0] += a * bb.x; acc[1] += a * bb.y;
        acc[2] += a * bb.z; acc[3] += a * bb.w;
      }
      __syncthreads();
    }
  }
  f4 o = {acc[0], acc[1], acc[2], acc[3]};
  wts4(&Q[(size_t)(bi * 32 + lr) * N + bj * 32 + lc], o);
}

// Vtr[base+c][n] = sum_k P[n][k]*Vtr[c][k].
__device__ void vstep_g(const float* __restrict__ P, float* __restrict__ Vtr,
                        int base, int first, int bi, int tid, float* sm) {
  float* As = sm;          // [32][33]
  float* Bs = sm + 1056;   // [32][33]
  int lr = tid >> 3, lc = (tid & 7) * 4;
  int cq = tid >> 3, n4 = (tid & 7) * 4;
  int nk = bi + 1;
  const float* ap = P + (size_t)(bi * 32 + lr) * N + lc;
  f4 aR[16];
#pragma unroll
  for (int t = 0; t < 16; ++t)
    if (t < nk) aR[t] = *(const f4*)(ap + 32 * t);
  int ncj = (base > 32) ? 2 : 1;
  for (int cj = 0; cj < ncj; ++cj) {
    int crow = cj * 32 + lr;
    int cok = (crow < base);
    const float* bp = Vtr + (size_t)crow * N + lc;
    f4 bR[16];
#pragma unroll
    for (int t = 0; t < 16; ++t)
      if (t < nk) bR[t] = cok ? *(const f4*)(bp + 32 * t) : (f4){0.f, 0.f, 0.f, 0.f};
    float acc[4] = {0.f, 0.f, 0.f, 0.f};
#pragma unroll
    for (int t = 0; t < 16; ++t) {
      if (t < nk) {
        int kb = 32 * t;
        float a4[4] = {aR[t].x, aR[t].y, aR[t].z, aR[t].w};
        if (first) {
#pragma unroll
          for (int j = 0; j < 4; ++j)
            a4[j] = 2.f * a4[j] - ((bi * 32 + lr == kb + lc + j) ? 1.f : 0.f);
        }
        As[lr * 33 + lc] = a4[0]; As[lr * 33 + lc + 1] = a4[1];
        As[lr * 33 + lc + 2] = a4[2]; As[lr * 33 + lc + 3] = a4[3];
        Bs[lr * 33 + lc] = bR[t].x; Bs[lr * 33 + lc + 1] = bR[t].y;
        Bs[lr * 33 + lc + 2] = bR[t].z; Bs[lr * 33 + lc + 3] = bR[t].w;
        __syncthreads();
#pragma unroll
        for (int kk = 0; kk < 32; ++kk) {
          float b = Bs[cq * 33 + kk];
          acc[0] += As[(n4 + 0) * 33 + kk] * b;
          acc[1] += As[(n4 + 1) * 33 + kk] * b;
          acc[2] += As[(n4 + 2) * 33 + kk] * b;
          acc[3] += As[(n4 + 3) * 33 + kk] * b;
        }
        __syncthreads();
      }
    }
    int c = cj * 32 + cq;
    if (c < base) {
      f4 o = {acc[0], acc[1], acc[2], acc[3]};
      wts4(&Vtr[(size_t)(base + c) * N + bi * 32 + n4], o);
    }
    if (cj + 1 < ncj) __syncthreads();
  }
}

// W[base+q][c] = sum_k W[q][k]*P[k][c], K from cj*32.
__device__ void wstep_g(const float* __restrict__ P, float* __restrict__ W,
                        int base, int cj, int tid, float* sm) {
  float* As = sm;
  float* Bs = sm + 1056;   // [32][36]
  int lr = tid >> 3, lc = (tid & 7) * 4;
  int kb0 = cj * 32, nk = 16 - cj;
  int qok = (lr < base);
  const float* ap = W + (size_t)lr * N + lc;
  const float* bp = P + cj * 32 + lc;
  f4 aR[16], bR[16];
#pragma unroll
  for (int t = 0; t < 16; ++t) {
    if (t < nk) {
      int kt = kb0 + 32 * t;
      aR[t] = qok ? *(const f4*)(ap + kt) : (f4){0.f, 0.f, 0.f, 0.f};
      bR[t] = *(const f4*)(bp + (size_t)(kt + lr) * N);
    }
  }
  float acc[4] = {0.f, 0.f, 0.f, 0.f};
#pragma unroll
  for (int t = 0; t < 16; ++t) {
    if (t < nk) {
      As[lr * 33 + lc] = aR[t].x; As[lr * 33 + lc + 1] = aR[t].y;
      As[lr * 33 + lc + 2] = aR[t].z; As[lr * 33 + lc + 3] = aR[t].w;
      *(f4*)&Bs[lr * 36 + lc] = bR[t];
      __syncthreads();
#pragma unroll
      for (int kk = 0; kk < 32; ++kk) {
        float a = As[lr * 33 + kk];
        f4 bb = *(const f4*)&Bs[kk * 36 + lc];
        acc[0] += a * bb.x; acc[1] += a * bb.y;
        acc[2] += a * bb.z; acc[3] += a * bb.w;
      }
      __syncthreads();
    }
  }
  if (lr < base) {
    f4 o = {acc[0], acc[1], acc[2], acc[3]};
    wts4(&W[(size_t)(base + lr) * N + cj * 32 + lc], o);
  }
}

// kvec[q][r] = sum_n W[q][n]*Vtr[r][n].
__device__ void kfinal_g(const float* __restrict__ W, const float* __restrict__ Vtr,
                         float* __restrict__ kvec, int bi, int bj, int tid, float* sm) {
  float* As = sm;
  float* Bs = sm + 1056;
  int lr = tid >> 3, lc = (tid & 7) * 4;
  int q = tid >> 3, r4 = (tid & 7) * 4;
  const float* ap = W + (size_t)(bi * 32 + lr) * N + lc;
  const float* bp = Vtr + (size_t)(bj * 32 + lr) * N + lc;
  f4 aR[16], bR[16];
#pragma unroll
  for (int t = 0; t < 16; ++t) {
    aR[t] = *(const f4*)(ap + 32 * t);
    bR[t] = *(const f4*)(bp + 32 * t);
  }
  float acc[4] = {0.f, 0.f, 0.f, 0.f};
#pragma unroll
  for (int t = 0; t < 16; ++t) {
    As[lr * 33 + lc] = aR[t].x; As[lr * 33 + lc + 1] = aR[t].y;
    As[lr * 33 + lc + 2] = aR[t].z; As[lr * 33 + lc + 3] = aR[t].w;
    Bs[lr * 33 + lc] = bR[t].x; Bs[lr * 33 + lc + 1] = bR[t].y;
    Bs[lr * 33 + lc + 2] = bR[t].z; Bs[lr * 33 + lc + 3] = bR[t].w;
    __syncthreads();
#pragma unroll
    for (int kk = 0; kk < 32; ++kk) {
      float a = As[q * 33 + kk];
      acc[0] += a * Bs[(r4 + 0) * 33 + kk];
      acc[1] += a * Bs[(r4 + 1) * 33 + kk];
      acc[2] += a * Bs[(r4 + 2) * 33 + kk];
      acc[3] += a * Bs[(r4 + 3) * 33 + kk];
    }
    __syncthreads();
  }
  f4 o = {acc[0], acc[1], acc[2], acc[3]};
  wts4(&kvec[(size_t)(bi * 32 + q) * 128 + bj * 32 + r4], o);
}

// Vtr[0][n] = delta*(Xi*Bm)[n]: 16 blocks x 32 rows.
__device__ void bd1_body(const float* __restrict__ Xi, const float* __restrict__ Bm,
                         float delta, float* __restrict__ Vtr, int bb, int tid,
                         float* sm) {
  float* bs = sm;
  if (tid < 128) ((f4*)bs)[tid] = ((const f4*)Bm)[tid];
  __syncthreads();
  int w = tid >> 6, lane = tid & 63;
#pragma unroll
  for (int pass = 0; pass < 8; ++pass) {
    int row = bb * 32 + w * 8 + pass;
    const float* Xr = Xi + (size_t)row * N + lane * 8;
    f4 a0 = *(const f4*)Xr;
    f4 a1 = *(const f4*)(Xr + 4);
    const float* bp = bs + lane * 8;
    float acc = a0.x * bp[0] + a0.y * bp[1] + a0.z * bp[2] + a0.w * bp[3]
              + a1.x * bp[4] + a1.y * bp[5] + a1.z * bp[6] + a1.w * bp[7];
    acc += __shfl_xor(acc, 1, 64);
    acc += __shfl_xor(acc, 2, 64);
    acc += __shfl_xor(acc, 4, 64);
    acc += __shfl_xor(acc, 8, 64);
    acc += __shfl_xor(acc, 16, 64);
    acc += __shfl_xor(acc, 32, 64);
    if (lane == 0) Vtr[row] = delta * acc;
  }
}

__device__ __forceinline__ void afrag_unit(const float* __restrict__ X,
                                           unsigned* __restrict__ Atab, int u) {
  int lane = u & 63;
  int f = u >> 6;
  int bt = f >> 8, ut = f & 255;
  int row = bt * 16 + (lane & 15);
  int u0 = ut * 32 + ((lane >> 4) << 3);
  const float* xp = X + (size_t)row * L + u0;
  unsigned short v[8];
#pragma unroll
  for (int e = 0; e < 8; ++e) v[e] = f2bf(xp[e]);
  u4 o = {pack2(v[0], v[1]), pack2(v[2], v[3]), pack2(v[4], v[5]), pack2(v[6], v[7])};
  wts4u(Atab + ((size_t)f * 64 + lane) * 4, o);
}

__device__ __forceinline__ void bfrag_unit(const float* __restrict__ kvec,
                                           unsigned* __restrict__ Btab, int u) {
  int lane = u & 63;
  int si = u >> 6;
  int base = si * 16 + (lane & 15) - ((lane >> 4) << 3);
  unsigned short v[8];
#pragma unroll
  for (int e = 0; e < 8; ++e) {
    int idx = base - e;
    float x = (idx >= 0) ? kvec[idx] : 0.0f;
    v[e] = f2bf(x);
  }
  u4 o = {pack2(v[0], v[1]), pack2(v[2], v[3]), pack2(v[4], v[5]), pack2(v[6], v[7])};
  wts4u(Btab + ((size_t)si * 64 + lane) * 4, o);
}

__device__ __forceinline__ void tridec(int b, int& bi, int& bj) {
  int sbi = 0, srem = b;
  while (srem > sbi) { srem -= (sbi + 1); ++sbi; }
  bi = sbi; bj = srem;
}

// --- phase kernels ----------------------------------------------------------

// P0: 0-15 diag32 inverses -> Dinv; 16: W[0]=C; 17-144: Atab fill. Grid 145.
__global__ __launch_bounds__(256, 1) void k_p0(const float* __restrict__ A,
                                               const float* __restrict__ C,
                                               const float* __restrict__ logd,
                                               const float* __restrict__ X,
                                               float* __restrict__ Dinv,
                                               float* __restrict__ W,
                                               unsigned* __restrict__ Atab) {
  int b = blockIdx.x, tid = threadIdx.x;
  if (b < 16) {
    diag32inv(A, 0.5f * get_delta(logd), Dinv, b, tid);
  } else if (b == 16) {
    for (int i = tid; i < N; i += 256) W[i] = C[i];
  } else {
    int u0 = (b - 17) * 512 + tid;
    afrag_unit(X, Atab, u0);
    afrag_unit(X, Atab, u0 + 256);
  }
}

// TINV: one 16-col panel of Xi = A1^-1 per block via blocked substitution.
// Grid 32. D_i X[i] = E_i + h*sum_{j<i} A[i][j] X[j];  X[i] = Dinv_i * (...).
__global__ __launch_bounds__(256, 1) void k_tinv(const float* __restrict__ A,
                                                 const float* __restrict__ logd,
                                                 const float* __restrict__ Dinv,
                                                 float* __restrict__ Xi) {
  __shared__ float Xp[512][16];   // 32KB panel
  int cp = blockIdx.x, tid = threadIdx.x;
  float h = 0.5f * get_delta(logd);
  int rr = tid >> 3, c2 = (tid & 7) * 2;
  for (int i = tid; i < 512 * 16; i += 256) ((float*)Xp)[i] = 0.f;
  __syncthreads();
  int istart = cp >> 1;
  int gc0 = cp * 16;
  for (int i = istart; i < 16; ++i) {
    float a0 = 0.f, a1 = 0.f;
    for (int j = istart; j < i; ++j) {
      const float* Arow = A + (size_t)(i * 32 + rr) * N + j * 32;
#pragma unroll
      for (int kk = 0; kk < 32; kk += 4) {
        f4 av = *(const f4*)(Arow + kk);
        int kb = j * 32 + kk;
        a0 += av.x * Xp[kb][c2] + av.y * Xp[kb + 1][c2]
            + av.z * Xp[kb + 2][c2] + av.w * Xp[kb + 3][c2];
        a1 += av.x * Xp[kb][c2 + 1] + av.y * Xp[kb + 1][c2 + 1]
            + av.z * Xp[kb + 2][c2 + 1] + av.w * Xp[kb + 3][c2 + 1];
      }
    }
    int grow = i * 32 + rr;
    float m0 = h * a0 + ((grow == gc0 + c2) ? 1.f : 0.f);
    float m1 = h * a1 + ((grow == gc0 + c2 + 1) ? 1.f : 0.f);
    __syncthreads();
    Xp[grow][c2] = m0;
    Xp[grow][c2 + 1] = m1;
    __syncthreads();
    float x0 = 0.f, x1 = 0.f;
    const float* Dv = Dinv + i * 1024 + rr * 32;
#pragma unroll
    for (int kk = 0; kk < 32; kk += 4) {
      f4 dv4 = *(const f4*)(Dv + kk);
      int kb = i * 32 + kk;
      x0 += dv4.x * Xp[kb][c2] + dv4.y * Xp[kb + 1][c2]
          + dv4.z * Xp[kb + 2][c2] + dv4.w * Xp[kb + 3][c2];
      x1 += dv4.x * Xp[kb][c2 + 1] + dv4.y * Xp[kb + 1][c2 + 1]
          + dv4.z * Xp[kb + 2][c2 + 1] + dv4.w * Xp[kb + 3][c2 + 1];
    }
    __syncthreads();
    Xp[grow][c2] = x0;
    Xp[grow][c2 + 1] = x1;
    __syncthreads();
  }
  for (int r0 = 0; r0 < 512; r0 += 32) {
    int row = r0 + rr;
    Xi[(size_t)row * N + gc0 + c2] = Xp[row][c2];
    Xi[(size_t)row * N + gc0 + c2 + 1] = Xp[row][c2 + 1];
  }
}

// sq1(first) || bd1. Grid 152.
__global__ __launch_bounds__(256, 1) void k_sqbd(const float* __restrict__ Xi,
                                                 float* __restrict__ Q,
                                                 const float* __restrict__ Bm,
                                                 const float* __restrict__ logd,
                                                 float* __restrict__ Vtr) {
  __shared__ float sm[2304];
  int b = blockIdx.x, tid = threadIdx.x;
  if (b < 136) {
    int bi, bj; tridec(b, bi, bj);
    sq32(Xi, Q, bi, bj, 1, tid, sm);
  } else {
    bd1_body(Xi, Bm, get_delta(logd), Vtr, b - 136, tid, sm);
  }
}

// sq || vstep. Grid 152.
__global__ __launch_bounds__(256, 1) void k_sqv(const float* __restrict__ P,
                                                float* __restrict__ Q,
                                                const float* __restrict__ Pv,
                                                float* __restrict__ Vtr,
                                                int base, int first) {
  __shared__ float sm[2304];
  int b = blockIdx.x, tid = threadIdx.x;
  if (b < 136) {
    int bi, bj; tridec(b, bi, bj);
    sq32(P, Q, bi, bj, 0, tid, sm);
  } else {
    vstep_g(Pv, Vtr, base, first, b - 136, tid, sm);
  }
}

// sq || vstep(64) || wstep(1). Grid 168.
__global__ __launch_bounds__(256, 1) void k_sqvw(const float* __restrict__ P,
                                                 float* __restrict__ Q,
                                                 const float* __restrict__ Pv,
                                                 float* __restrict__ Vtr,
                                                 const float* __restrict__ Pw,
                                                 float* __restrict__ W) {
  __shared__ float sm[2304];
  int b = blockIdx.x, tid = threadIdx.x;
  if (b < 136) {
    int bi, bj; tridec(b, bi, bj);
    sq32(P, Q, bi, bj, 0, tid, sm);
  } else if (b < 152) {
    vstep_g(Pv, Vtr, 64, 0, b - 136, tid, sm);
  } else {
    wstep_g(Pw, W, 1, b - 152, tid, sm);
  }
}

// sq || wstep. Grid 152.
__global__ __launch_bounds__(256, 1) void k_sqw(const float* __restrict__ P,
                                                float* __restrict__ Q,
                                                const float* __restrict__ Pw,
                                                float* __restrict__ W,
                                                int base) {
  __shared__ float sm[2304];
  int b = blockIdx.x, tid = threadIdx.x;
  if (b < 136) {
    int bi, bj; tridec(b, bi, bj);
    sq32(P, Q, bi, bj, 0, tid, sm);
  } else {
    wstep_g(Pw, W, base, b - 136, tid, sm);
  }
}

// wstep only (w32). Grid 16.
__global__ __launch_bounds__(256, 1) void k_wf(const float* __restrict__ Pw,
                                               float* __restrict__ W, int base) {
  __shared__ float sm[2304];
  wstep_g(Pw, W, base, blockIdx.x, threadIdx.x, sm);
}

// kfinal. Grid 8.
__global__ __launch_bounds__(256, 1) void k_kf(const float* __restrict__ W,
                                               const float* __restrict__ Vtr,
                                               float* __restrict__ kvec) {
  __shared__ float sm[2304];
  kfinal_g(W, Vtr, kvec, blockIdx.x >> 2, blockIdx.x & 3, threadIdx.x, sm);
}

// bfrag. Grid 128.
__global__ __launch_bounds__(256, 1) void k_bf(const float* __restrict__ kvec,
                                               unsigned* __restrict__ Btab) {
  bfrag_unit(kvec, Btab, blockIdx.x * 256 + threadIdx.x);
}

// Conv: 1024 blocks x 4 waves. Block (p, sub): j = (sub&1)? 511-p : p,
// bt-pair = sub>>1. Waves: bt = pair*2 + (w&1), kh = w>>1 (2-way split-K).
__global__ __launch_bounds__(256, 1) void k_convmm(const short8* __restrict__ Atab,
                                                   const short8* __restrict__ Btab,
                                                   const float* __restrict__ X,
                                                   const float* __restrict__ Dp,
                                                   float* __restrict__ Y) {
  __shared__ f4 red[2][64];
  int tid = threadIdx.x, lane = tid & 63, w = tid >> 6;
  int bid = blockIdx.x;
  int p = bid >> 2, sub = bid & 3;
  int j = (sub & 1) ? (511 - p) : p;
  int bt = ((sub >> 1) << 1) | (w & 1);
  int kh = w >> 1;
  int nt = (j + 2) >> 1;
  f4 acc = {0.f, 0.f, 0.f, 0.f};
  const short8* Ab = Atab + (size_t)bt * 256 * 64 + lane;
  const short8* Bb = Btab + lane;
  for (int ut = kh; ut < nt; ut += 2) {
    short8 a = Ab[(size_t)ut * 64];
    short8 bf = Bb[(size_t)(j - 2 * ut) * 64];
    acc = __builtin_amdgcn_mfma_f32_16x16x32_bf16(a, bf, acc, 0, 0, 0);
  }
  if (kh == 1) red[w & 1][lane] = acc;
  __syncthreads();
  if (kh == 0) {
    f4 o = red[w & 1][lane];
    float D0 = Dp[0];
    int tt = lane & 15, rq = (lane >> 4) << 2;
#pragma unroll
    for (int r = 0; r < 4; ++r) {
      int row = bt * 16 + rq + r;
      size_t off = (size_t)row * L + j * 16 + tt;
      Y[off] = acc[r] + o[r] + D0 * X[off];
    }
  }
}

extern "C" void kernel_launch(void* const* d_in, const int* in_sizes, int n_in,
                              void* d_out, int out_size, void* d_ws, size_t ws_size,
                              hipStream_t stream) {
  const float* X  = (const float*)d_in[0];
  const float* A  = (const float*)d_in[1];
  const float* Bm = (const float*)d_in[2];
  const float* C  = (const float*)d_in[3];
  const float* D  = (const float*)d_in[4];
  const float* ld = (const float*)d_in[5];
  float* Y = (float*)d_out;

  float* ws = (float*)d_ws;
  float* kv   = ws;                 // 8192
  float* Vtr  = ws + 8192;          // 128*512
  float* W    = ws + 73728;         // 64*512
  float* Xi   = ws + 106496;        // 512*512
  float* PB   = ws + 368640;        // 12*512*512
  unsigned* Atab = (unsigned*)(ws + 3514368);
  unsigned* Btab = (unsigned*)(ws + 3776512);
  float* Dinv = ws + 3907584;       // 16*1024
#define PBUF(i) (PB + (size_t)(i) * (N * N))

  k_p0<<<145, 256, 0, stream>>>(A, C, ld, X, Dinv, W, Atab);
  k_tinv<<<32, 256, 0, stream>>>(A, ld, Dinv, Xi);

  k_sqbd<<<152, 256, 0, stream>>>(Xi, PBUF(0), Bm, ld, Vtr);
  k_sqv<<<152, 256, 0, stream>>>(PBUF(0), PBUF(1), Xi, Vtr, 1, 1);      // sq2 + v1
  k_sqv<<<152, 256, 0, stream>>>(PBUF(1), PBUF(2), PBUF(0), Vtr, 2, 0); // sq3 + v2
  k_sqv<<<152, 256, 0, stream>>>(PBUF(2), PBUF(3), PBUF(1), Vtr, 4, 0); // sq4 + v4
  k_sqv<<<152, 256, 0, stream>>>(PBUF(3), PBUF(4), PBUF(2), Vtr, 8, 0); // sq5 + v8
  k_sqv<<<152, 256, 0, stream>>>(PBUF(4), PBUF(5), PBUF(3), Vtr, 16, 0);// sq6 + v16
  k_sqv<<<152, 256, 0, stream>>>(PBUF(5), PBUF(6), PBUF(4), Vtr, 32, 0);// sq7 + v32
  k_sqvw<<<168, 256, 0, stream>>>(PBUF(6), PBUF(7), PBUF(5), Vtr, PBUF(6), W); // sq8 + v64 + w1
  k_sqw<<<152, 256, 0, stream>>>(PBUF(7), PBUF(8), PBUF(7), W, 2);      // sq9 + w2
  k_sqw<<<152, 256, 0, stream>>>(PBUF(8), PBUF(9), PBUF(8), W, 4);      // sq10 + w4
  k_sqw<<<152, 256, 0, stream>>>(PBUF(9), PBUF(10), PBUF(9), W, 8);     // sq11 + w8
  k_sqw<<<152, 256, 0, stream>>>(PBUF(10), PBUF(11), PBUF(10), W, 16);  // sq12 + w16
  k_wf<<<16, 256, 0, stream>>>(PBUF(11), W, 32);                        // w32
  k_kf<<<8, 256, 0, stream>>>(W, Vtr, kv);
  k_bf<<<128, 256, 0, stream>>>(kv, Btab);
  k_convmm<<<1024, 256, 0, stream>>>((const short8*)Atab, (const short8*)Btab, X, D, Y);
#undef PBUF
}